// Round 18
// baseline (424.950 us; speedup 1.0000x reference)
//
#include <hip/hip_runtime.h>
#include <hip/hip_bf16.h>

// CrossAttention: q = x@Wq+bq; k = cond@Wk+bk; v = cond@Wv+bv
// scores = q@k^T (UNSCALED); attn = softmax(scores); out = attn@v
// B=4, Lq=Lk=4096, IN=COND=256, OUT_DIM=128. Output fp32.
//
// r18: r10 per-wave loop UNCHANGED; NSPLIT 4->8 with 512-thr blocks so the
// grid fills the chip's wave slots: 2 blocks/CU x 8 waves = 16 waves/CU =
// 4/SIMD (r10-r17 ran 2/SIMD -- the grid, not registers, capped occupancy).
// Same total L2 traffic; combine tree extends to 8 partials (r8's tree).

typedef __attribute__((ext_vector_type(8))) short short8;
typedef __attribute__((ext_vector_type(8))) unsigned short ushort8;
typedef __attribute__((ext_vector_type(4))) unsigned short us4;
typedef __attribute__((ext_vector_type(4))) float f32x4;
typedef __attribute__((ext_vector_type(16))) float f32x16;
typedef __attribute__((ext_vector_type(4))) unsigned int u32x4;
typedef __bf16 bf16x8 __attribute__((ext_vector_type(8)));

constexpr int BATCH  = 4;
constexpr int SEQLEN = 4096;   // Lq == Lk
constexpr int DIN    = 256;
constexpr int DOUT   = 128;
constexpr int ROWS   = BATCH * SEQLEN;  // 16384
constexpr float LOG2E = 1.4426950408889634f;

static __device__ __forceinline__ unsigned short bf16_rn(float f) {
  unsigned int u = __builtin_bit_cast(unsigned int, f);
  unsigned int r = u + 0x7FFFu + ((u >> 16) & 1u);
  return (unsigned short)(r >> 16);
}
static __device__ __forceinline__ float bf16_f32(unsigned short h) {
  return __builtin_bit_cast(float, (unsigned int)h << 16);
}
static __device__ __forceinline__ float exp2n(float x) {
  return __builtin_amdgcn_exp2f(x);    // native v_exp_f32
}

static __device__ __forceinline__ f32x4 mfma_bf16(short8 a, short8 b, f32x4 c) {
  return __builtin_amdgcn_mfma_f32_16x16x32_bf16(
      __builtin_bit_cast(bf16x8, a), __builtin_bit_cast(bf16x8, b), c, 0, 0, 0);
}
static __device__ __forceinline__ f32x16 mfma32(short8 a, short8 b, f32x16 c) {
  return __builtin_amdgcn_mfma_f32_32x32x16_bf16(
      __builtin_bit_cast(bf16x8, a), __builtin_bit_cast(bf16x8, b), c, 0, 0, 0);
}

// D = [bf16(S0) | bf16(S1)<<16]
static __device__ __forceinline__ unsigned int cvt_pk(float lo, float hi) {
  unsigned int r;
  asm("v_cvt_pk_bf16_f32 %0, %1, %2" : "=v"(r) : "v"(lo), "v"(hi));
  return r;
}
// v_permlane32_swap_b32 vdst, vsrc: a.hi32lanes <-> b.lo32lanes
static __device__ __forceinline__ void permswap(unsigned int& a, unsigned int& b) {
  asm("v_permlane32_swap_b32 %0, %1" : "+v"(a), "+v"(b));
}

static __device__ __forceinline__ int swz128(int a) {
  return a ^ (((a >> 7) & 7) << 4);
}
// K-bounce tile (row stride 256B): fold row bits 0-3 into byte bits 4-7
static __device__ __forceinline__ int swzK(int a) {
  return a ^ (((a >> 8) & 15) << 4);
}

// Fragment-major global layouts (written by proj, read coalesced by attn):
//  K: kfb[b][kblk(128)][f(8)][lane(64)] x 16B
//  V: vfb[b][kblk(128)][dblk(4)][kk(2)][lane(64)] x 16B

// ---------------- projection via MFMA, split-precision --------------------
__global__ __launch_bounds__(256) void proj_kernel(
    const float* __restrict__ x, const float* __restrict__ cond,
    const float* __restrict__ Wq, const float* __restrict__ bq,
    const float* __restrict__ Wk, const float* __restrict__ bk,
    const float* __restrict__ Wv, const float* __restrict__ bv,
    unsigned short* __restrict__ qb, unsigned short* __restrict__ kb,
    unsigned short* __restrict__ vt)
{
  const int which = blockIdx.y;
  const float* __restrict__ src  = (which == 0) ? x  : cond;
  const float* __restrict__ W    = (which == 0) ? Wq : (which == 1 ? Wk : Wv);
  const float* __restrict__ bias = (which == 0) ? bq : (which == 1 ? bk : bv);
  const int r0 = blockIdx.x * 64;

  __shared__ __align__(16) char lds[32768];
  char* const AhB = lds;
  char* const AlB = lds + 8192;
  char* const WtB = lds + 16384;

  const int tid  = threadIdx.x;
  const int wv   = tid >> 6;
  const int lane = tid & 63;
  const int g    = lane >> 4;
  const int c    = lane & 15;

  f32x4 acc[8];
  #pragma unroll
  for (int cf = 0; cf < 8; ++cf) acc[cf] = (f32x4){0.f, 0.f, 0.f, 0.f};

  for (int kt = 0; kt < 4; ++kt) {
    #pragma unroll
    for (int i = 0; i < 4; ++i) {
      const int idx = tid + i * 256;
      const int row = idx >> 4, f4 = idx & 15;
      const float4 a4 =
          *(const float4*)(src + (size_t)(r0 + row) * DIN + kt * 64 + f4 * 4);
      us4 hi, lo;
      const float av[4] = {a4.x, a4.y, a4.z, a4.w};
      #pragma unroll
      for (int e = 0; e < 4; ++e) {
        hi[e] = bf16_rn(av[e]);
        lo[e] = bf16_rn(av[e] - bf16_f32(hi[e]));
      }
      const int off = swz128(row * 128 + f4 * 8);
      *(us4*)(AhB + off) = hi;
      *(us4*)(AlB + off) = lo;
    }
    {
      const int col = tid & 127, half = tid >> 7;
      #pragma unroll
      for (int j = 0; j < 4; ++j) {
        const int k0 = half * 32 + j * 8;
        ushort8 wb;
        #pragma unroll
        for (int e = 0; e < 8; ++e)
          wb[e] = bf16_rn(W[(size_t)(kt * 64 + k0 + e) * DOUT + col]);
        *(ushort8*)(WtB + swz128(col * 128 + k0 * 2)) = wb;
      }
    }
    __syncthreads();

    #pragma unroll
    for (int ks = 0; ks < 2; ++ks) {
      const int aoff = (wv * 16 + c) * 128 + ks * 64 + g * 16;
      const short8 ah = *(const short8*)(AhB + swz128(aoff));
      const short8 al = *(const short8*)(AlB + swz128(aoff));
      #pragma unroll
      for (int cf = 0; cf < 8; ++cf) {
        const short8 wb =
            *(const short8*)(WtB + swz128((cf * 16 + c) * 128 + ks * 64 + g * 16));
        acc[cf] = mfma_bf16(ah, wb, acc[cf]);
        acc[cf] = mfma_bf16(al, wb, acc[cf]);
      }
    }
    __syncthreads();
  }

  if (which == 0) {
    // q scaled by log2(e) in f32 BEFORE the bf16 round (exp2-domain softmax)
    #pragma unroll
    for (int cf = 0; cf < 8; ++cf) {
      const float bb = bias[cf * 16 + c];
      #pragma unroll
      for (int r = 0; r < 4; ++r)
        qb[(size_t)(r0 + wv * 16 + g * 4 + r) * DOUT + cf * 16 + c] =
            bf16_rn((acc[cf][r] + bb) * LOG2E);
    }
  } else if (which == 1) {
    // K: bounce through swizzled LDS tile, then coalesced fragment-major stores
    char* const Ktile = lds;   // 16KB
    #pragma unroll
    for (int cf = 0; cf < 8; ++cf) {
      const float bb = bias[cf * 16 + c];
      #pragma unroll
      for (int r = 0; r < 4; ++r) {
        const int row = wv * 16 + g * 4 + r;
        *(unsigned short*)(Ktile + swzK(row * 256 + (cf * 16 + c) * 2)) =
            bf16_rn(acc[cf][r] + bb);
      }
    }
    __syncthreads();
    const int b2     = r0 >> 12;
    const int kblkG0 = (r0 & 4095) >> 5;
    #pragma unroll
    for (int j = 0; j < 4; ++j) {
      const int i    = tid + j * 256;
      const int kblk = i >> 9;
      const int rem  = i & 511;
      const int f    = rem >> 6;
      const int ln   = rem & 63;
      const int row  = kblk * 32 + (ln & 31);
      const int colb = f * 32 + (ln >> 5) * 16;
      const ushort8 v = *(const ushort8*)(Ktile + swzK(row * 256 + colb));
      *(ushort8*)((char*)kb +
          (((size_t)(b2 * 128 + kblkG0 + kblk) * 8 + f) * 64 + ln) * 16) = v;
    }
  } else {
    // fragment-major V (4 consecutive keys -> one us4 store)
    const int keybase = r0 + wv * 16 + g * 4;
    const int b2   = keybase >> 12;
    const int kblk = (keybase & 4095) >> 5;
    const int kk   = (keybase >> 4) & 1;
    const int h    = (keybase >> 3) & 1;
    const int e0   = keybase & 7;
    #pragma unroll
    for (int cf = 0; cf < 8; ++cf) {
      const float bb = bias[cf * 16 + c];
      const int col  = cf * 16 + c;
      const int dblk = col >> 5, l31 = col & 31;
      us4 pk;
      #pragma unroll
      for (int r = 0; r < 4; ++r) pk[r] = bf16_rn(acc[cf][r] + bb);
      *(us4*)(vt + (((((size_t)b2 * 128 + kblk) * 4 + dblk) * 2 + kk) * 64 +
                    h * 32 + l31) * 8 + e0) = pk;
    }
  }
}

// ---------------- flash attention: r10 loop, 8-way split, 4 waves/SIMD ----
// Block: 512 thr = 8 waves = 8 kv-splits of one 32-query tile.
// Wave: 32 q x 512 keys, KVBLK=32/iter (16 iters), 32x32x16 MFMA.
// Grid 512 x 2 blocks/CU (68KB LDS) -> 16 waves/CU = 4/SIMD.
constexpr int NSPLIT = 8;
constexpr int QBLK   = 32;
constexpr int KVBLK  = 32;
constexpr int ITERS  = SEQLEN / NSPLIT / KVBLK;   // 16 (even)

__global__ __launch_bounds__(512, 4) void attn_kernel(
    const unsigned short* __restrict__ qb,
    const unsigned short* __restrict__ kb,
    const unsigned short* __restrict__ vt,
    float* __restrict__ out)
{
  __shared__ __align__(16) float cmb[4][32][132];   // 67.6KB combine regions
  __shared__ float Ml[NSPLIT][32][2];               // 2KB

  // XCD swizzle (512 blocks = 8 XCD x 64): one batch per XCD-pair -> L2-fit
  const int bid = ((blockIdx.x & 7) << 6) | (blockIdx.x >> 3);
  const int qt  = bid & 127;
  const int b   = bid >> 7;
  const int tid = threadIdx.x;
  const int split = tid >> 6;   // 0..7
  const int lane  = tid & 63;
  const int ql = lane & 31;   // query column this lane owns
  const int h  = lane >> 5;   // half-wave

  const int q0 = qt * QBLK;

  // ---- Q B-fragments (once) ----
  short8 qf[8];
  {
    const char* qp = (const char*)(qb + (size_t)(b * SEQLEN + q0 + ql) * DOUT) + h * 16;
    #pragma unroll
    for (int f = 0; f < 8; ++f) qf[f] = *(const short8*)(qp + f * 32);
  }

  // ---- fragment-major streaming bases ----
  const int kblk0 = split * (SEQLEN / NSPLIT / 32);   // split*16
  const char* kfb = (const char*)kb + ((size_t)b * 128 + kblk0) * 8192 + lane * 16;
  const char* vfb = (const char*)vt + ((size_t)b * 128 + kblk0) * 8192 + lane * 16;

  f32x16 acc[4];
  #pragma unroll
  for (int d = 0; d < 4; ++d)
    #pragma unroll
    for (int r = 0; r < 16; ++r) acc[d][r] = 0.f;
  float mc = -1e30f, lc = 0.f;

  // preload: K tiles 0,1 (A,B); V tile 0
  short8 kfA[8], kfB[8], vf[4][2];
  #pragma unroll
  for (int f = 0; f < 8; ++f) kfA[f] = *(const short8*)(kfb + f * 1024);
  #pragma unroll
  for (int f = 0; f < 8; ++f) kfB[f] = *(const short8*)(kfb + 8192 + f * 1024);
  kfb += 16384;                                   // -> tile 2
  #pragma unroll
  for (int d = 0; d < 4; ++d)
    #pragma unroll
    for (int kk = 0; kk < 2; ++kk)
      vf[d][kk] = *(const short8*)(vfb + (d * 2 + kk) * 1024);

  auto body = [&](short8 (&kf)[8], int t) {
    // ---- S^T = K Q^T, two independent chains (4-deep each) ----
    f32x16 s0, s1;
    #pragma unroll
    for (int r = 0; r < 16; ++r) { s0[r] = 0.f; s1[r] = 0.f; }
    __builtin_amdgcn_s_setprio(1);
    #pragma unroll
    for (int f = 0; f < 4; ++f) s0 = mfma32(kf[f], qf[f], s0);
    #pragma unroll
    for (int f = 0; f < 4; ++f) s1 = mfma32(kf[f + 4], qf[f + 4], s1);
    __builtin_amdgcn_s_setprio(0);

    // prefetch K(t+2) into the buffer just consumed (depth-2)
    if (t + 2 < ITERS) {
      #pragma unroll
      for (int f = 0; f < 8; ++f) kf[f] = *(const short8*)(kfb + f * 1024);
      kfb += 8192;
    }

    float s[16];
    #pragma unroll
    for (int r = 0; r < 16; ++r) s[r] = s0[r] + s1[r];

    // ---- softmax, defer-max (THR=11 log2 units: P <= 2048) ----
    float m01 = fmaxf(fmaxf(s[0],  s[1]),  s[2]);
    float m02 = fmaxf(fmaxf(s[3],  s[4]),  s[5]);
    float m03 = fmaxf(fmaxf(s[6],  s[7]),  s[8]);
    float m04 = fmaxf(fmaxf(s[9],  s[10]), s[11]);
    float m05 = fmaxf(fmaxf(s[12], s[13]), s[14]);
    float m11 = fmaxf(fmaxf(m01, m02), m03);
    float m12 = fmaxf(fmaxf(m04, m05), s[15]);
    float tm  = fmaxf(m11, m12);
    if (!__all(tm <= mc + 11.f)) {
      float tr = fmaxf(tm, __shfl_xor(tm, 32));
      const float mnew  = fmaxf(mc, tr);
      const float sc    = exp2n(mc - mnew);
      mc = mnew;
      lc *= sc;
      #pragma unroll
      for (int d = 0; d < 4; ++d)
        #pragma unroll
        for (int r = 0; r < 16; ++r) acc[d][r] *= sc;
    }
    float p[16];
    #pragma unroll
    for (int r = 0; r < 16; ++r) p[r] = exp2n(s[r] - mc);   // native v_exp_f32
    float a0 = (p[0]+p[1]) + (p[2]+p[3]);
    float a1 = (p[4]+p[5]) + (p[6]+p[7]);
    float a2 = (p[8]+p[9]) + (p[10]+p[11]);
    float a3 = (p[12]+p[13]) + (p[14]+p[15]);
    lc += (a0 + a1) + (a2 + a3);

    // ---- P -> B-fragments in-register (T12) ----
    short8 pfrag[2];
    #pragma unroll
    for (int kk = 0; kk < 2; ++kk) {
      unsigned int A  = cvt_pk(p[kk * 8 + 0], p[kk * 8 + 1]);
      unsigned int Bv = cvt_pk(p[kk * 8 + 2], p[kk * 8 + 3]);
      unsigned int C  = cvt_pk(p[kk * 8 + 4], p[kk * 8 + 5]);
      unsigned int Dv = cvt_pk(p[kk * 8 + 6], p[kk * 8 + 7]);
      permswap(A, C);
      permswap(Bv, Dv);
      const u32x4 w = {A, Bv, C, Dv};
      pfrag[kk] = __builtin_bit_cast(short8, w);
    }

    // ---- O^T += V^T P^T (4 independent 2-deep chains) ----
    __builtin_amdgcn_s_setprio(1);
    #pragma unroll
    for (int d = 0; d < 4; ++d)
      #pragma unroll
      for (int kk = 0; kk < 2; ++kk)
        acc[d] = mfma32(vf[d][kk], pfrag[kk], acc[d]);
    __builtin_amdgcn_s_setprio(0);

    // prefetch V(t+1)
    if (t + 1 < ITERS) {
      vfb += 8192;
      #pragma unroll
      for (int d = 0; d < 4; ++d)
        #pragma unroll
        for (int kk = 0; kk < 2; ++kk)
          vf[d][kk] = *(const short8*)(vfb + (d * 2 + kk) * 1024);
    }
  };

  for (int t = 0; t < ITERS; t += 2) {
    body(kfA, t);
    body(kfB, t + 1);
  }

  // ---- cross-split combine (exp2 domain), 8 partials ----
  lc += __shfl_xor(lc, 32);
  if (lane < 32) { Ml[split][ql][0] = mc; Ml[split][ql][1] = lc; }
  __syncthreads();

  float mg = -1e30f, lsum = 0.f;
  #pragma unroll
  for (int s2 = 0; s2 < NSPLIT; ++s2) mg = fmaxf(mg, Ml[s2][ql][0]);
  #pragma unroll
  for (int s2 = 0; s2 < NSPLIT; ++s2)
    lsum += Ml[s2][ql][1] * exp2n(Ml[s2][ql][0] - mg);
  const float fac = exp2n(mc - mg);
  #pragma unroll
  for (int d = 0; d < 4; ++d)
    #pragma unroll
    for (int r = 0; r < 16; ++r) acc[d][r] *= fac;

  auto writeReg = [&](float* reg) {
    #pragma unroll
    for (int d = 0; d < 4; ++d)
      #pragma unroll
      for (int rr = 0; rr < 4; ++rr) {
        const f32x4 v = {acc[d][rr*4+0], acc[d][rr*4+1], acc[d][rr*4+2], acc[d][rr*4+3]};
        *(f32x4*)(reg + ql * 132 + d * 32 + rr * 8 + h * 4) = v;
      }
  };
  auto addReg = [&](const float* reg) {
    #pragma unroll
    for (int d = 0; d < 4; ++d)
      #pragma unroll
      for (int rr = 0; rr < 4; ++rr) {
        const f32x4 v = *(const f32x4*)(reg + ql * 132 + d * 32 + rr * 8 + h * 4);
        acc[d][rr*4+0] += v.x; acc[d][rr*4+1] += v.y;
        acc[d][rr*4+2] += v.z; acc[d][rr*4+3] += v.w;
      }
  };

  // tree: {4-7} write -> {0-3} add -> {2,3} write -> {0,1} add
  //       -> {1} writes -> {0} adds -> out
  if (split >= 4) writeReg(&cmb[split - 4][0][0]);
  __syncthreads();
  if (split < 4) addReg(&cmb[split][0][0]);
  __syncthreads();
  if (split == 2 || split == 3) writeReg(&cmb[split - 2][0][0]);
  __syncthreads();
  if (split == 0 || split == 1) addReg(&cmb[split][0][0]);
  __syncthreads();
  if (split == 1) writeReg(&cmb[0][0][0]);
  __syncthreads();
  if (split == 0) {
    addReg(&cmb[0][0][0]);
    const float inv = 1.f / lsum;
    float* const op = out + (size_t)(b * SEQLEN + q0 + ql) * DOUT;
    #pragma unroll
    for (int d = 0; d < 4; ++d)
      #pragma unroll
      for (int rr = 0; rr < 4; ++rr) {
        f32x4 o;
        o.x = acc[d][rr*4+0] * inv;
        o.y = acc[d][rr*4+1] * inv;
        o.z = acc[d][rr*4+2] * inv;
        o.w = acc[d][rr*4+3] * inv;
        *(f32x4*)(op + d * 32 + rr * 8 + h * 4) = o;
      }
  }
}

extern "C" void kernel_launch(void* const* d_in, const int* in_sizes, int n_in,
                              void* d_out, int out_size, void* d_ws, size_t ws_size,
                              hipStream_t stream) {
  const float* x    = (const float*)d_in[0];
  const float* cond = (const float*)d_in[1];
  const float* Wq   = (const float*)d_in[2];
  const float* bq   = (const float*)d_in[3];
  const float* Wk   = (const float*)d_in[4];
  const float* bk   = (const float*)d_in[5];
  const float* Wv   = (const float*)d_in[6];
  const float* bv   = (const float*)d_in[7];
  float* out = (float*)d_out;

  unsigned short* qb = (unsigned short*)d_ws;                 // 4MB (log2e-scaled)
  unsigned short* kb = qb + (size_t)ROWS * DOUT;              // 4MB fragment-major
  unsigned short* vt = kb + (size_t)ROWS * DOUT;              // 4MB fragment-major

  proj_kernel<<<dim3(ROWS / 64, 3), 256, 0, stream>>>(
      x, cond, Wq, bq, Wk, bk, Wv, bv, qb, kb, vt);

  attn_kernel<<<dim3(BATCH * (SEQLEN / QBLK)), 512, 0, stream>>>(
      qb, kb, vt, out);
}

// Round 19
// 74.490 us; speedup vs baseline: 5.7048x; 5.7048x over previous
//
#include <hip/hip_runtime.h>
#include <hip/hip_bf16.h>

// CrossAttention: q = x@Wq+bq; k = cond@Wk+bk; v = cond@Wv+bv
// scores = q@k^T (UNSCALED); attn = softmax(scores); out = attn@v
// B=4, Lq=Lk=4096, IN=COND=256, OUT_DIM=128. Output fp32.
//
// r19 = r18 with PLAIN __launch_bounds__(512): r8/r18 proved the min-waves
// clause forces a spill (VGPR 64, 1.8GB scratch); r14 proved plain 512 does
// not. LDS 69.6KB caps residency at 2 blocks/CU = 4 waves/SIMD, which the
// compiler's natural 128-VGPR target supports without spill (r10-r17).

typedef __attribute__((ext_vector_type(8))) short short8;
typedef __attribute__((ext_vector_type(8))) unsigned short ushort8;
typedef __attribute__((ext_vector_type(4))) unsigned short us4;
typedef __attribute__((ext_vector_type(4))) float f32x4;
typedef __attribute__((ext_vector_type(16))) float f32x16;
typedef __attribute__((ext_vector_type(4))) unsigned int u32x4;
typedef __bf16 bf16x8 __attribute__((ext_vector_type(8)));

constexpr int BATCH  = 4;
constexpr int SEQLEN = 4096;   // Lq == Lk
constexpr int DIN    = 256;
constexpr int DOUT   = 128;
constexpr int ROWS   = BATCH * SEQLEN;  // 16384
constexpr float LOG2E = 1.4426950408889634f;

static __device__ __forceinline__ unsigned short bf16_rn(float f) {
  unsigned int u = __builtin_bit_cast(unsigned int, f);
  unsigned int r = u + 0x7FFFu + ((u >> 16) & 1u);
  return (unsigned short)(r >> 16);
}
static __device__ __forceinline__ float bf16_f32(unsigned short h) {
  return __builtin_bit_cast(float, (unsigned int)h << 16);
}
static __device__ __forceinline__ float exp2n(float x) {
  return __builtin_amdgcn_exp2f(x);    // native v_exp_f32
}

static __device__ __forceinline__ f32x4 mfma_bf16(short8 a, short8 b, f32x4 c) {
  return __builtin_amdgcn_mfma_f32_16x16x32_bf16(
      __builtin_bit_cast(bf16x8, a), __builtin_bit_cast(bf16x8, b), c, 0, 0, 0);
}
static __device__ __forceinline__ f32x16 mfma32(short8 a, short8 b, f32x16 c) {
  return __builtin_amdgcn_mfma_f32_32x32x16_bf16(
      __builtin_bit_cast(bf16x8, a), __builtin_bit_cast(bf16x8, b), c, 0, 0, 0);
}

// D = [bf16(S0) | bf16(S1)<<16]
static __device__ __forceinline__ unsigned int cvt_pk(float lo, float hi) {
  unsigned int r;
  asm("v_cvt_pk_bf16_f32 %0, %1, %2" : "=v"(r) : "v"(lo), "v"(hi));
  return r;
}
// v_permlane32_swap_b32 vdst, vsrc: a.hi32lanes <-> b.lo32lanes
static __device__ __forceinline__ void permswap(unsigned int& a, unsigned int& b) {
  asm("v_permlane32_swap_b32 %0, %1" : "+v"(a), "+v"(b));
}

static __device__ __forceinline__ int swz128(int a) {
  return a ^ (((a >> 7) & 7) << 4);
}
// K-bounce tile (row stride 256B): fold row bits 0-3 into byte bits 4-7
static __device__ __forceinline__ int swzK(int a) {
  return a ^ (((a >> 8) & 15) << 4);
}

// Fragment-major global layouts (written by proj, read coalesced by attn):
//  K: kfb[b][kblk(128)][f(8)][lane(64)] x 16B
//  V: vfb[b][kblk(128)][dblk(4)][kk(2)][lane(64)] x 16B

// ---------------- projection via MFMA, split-precision --------------------
__global__ __launch_bounds__(256) void proj_kernel(
    const float* __restrict__ x, const float* __restrict__ cond,
    const float* __restrict__ Wq, const float* __restrict__ bq,
    const float* __restrict__ Wk, const float* __restrict__ bk,
    const float* __restrict__ Wv, const float* __restrict__ bv,
    unsigned short* __restrict__ qb, unsigned short* __restrict__ kb,
    unsigned short* __restrict__ vt)
{
  const int which = blockIdx.y;
  const float* __restrict__ src  = (which == 0) ? x  : cond;
  const float* __restrict__ W    = (which == 0) ? Wq : (which == 1 ? Wk : Wv);
  const float* __restrict__ bias = (which == 0) ? bq : (which == 1 ? bk : bv);
  const int r0 = blockIdx.x * 64;

  __shared__ __align__(16) char lds[32768];
  char* const AhB = lds;
  char* const AlB = lds + 8192;
  char* const WtB = lds + 16384;

  const int tid  = threadIdx.x;
  const int wv   = tid >> 6;
  const int lane = tid & 63;
  const int g    = lane >> 4;
  const int c    = lane & 15;

  f32x4 acc[8];
  #pragma unroll
  for (int cf = 0; cf < 8; ++cf) acc[cf] = (f32x4){0.f, 0.f, 0.f, 0.f};

  for (int kt = 0; kt < 4; ++kt) {
    #pragma unroll
    for (int i = 0; i < 4; ++i) {
      const int idx = tid + i * 256;
      const int row = idx >> 4, f4 = idx & 15;
      const float4 a4 =
          *(const float4*)(src + (size_t)(r0 + row) * DIN + kt * 64 + f4 * 4);
      us4 hi, lo;
      const float av[4] = {a4.x, a4.y, a4.z, a4.w};
      #pragma unroll
      for (int e = 0; e < 4; ++e) {
        hi[e] = bf16_rn(av[e]);
        lo[e] = bf16_rn(av[e] - bf16_f32(hi[e]));
      }
      const int off = swz128(row * 128 + f4 * 8);
      *(us4*)(AhB + off) = hi;
      *(us4*)(AlB + off) = lo;
    }
    {
      const int col = tid & 127, half = tid >> 7;
      #pragma unroll
      for (int j = 0; j < 4; ++j) {
        const int k0 = half * 32 + j * 8;
        ushort8 wb;
        #pragma unroll
        for (int e = 0; e < 8; ++e)
          wb[e] = bf16_rn(W[(size_t)(kt * 64 + k0 + e) * DOUT + col]);
        *(ushort8*)(WtB + swz128(col * 128 + k0 * 2)) = wb;
      }
    }
    __syncthreads();

    #pragma unroll
    for (int ks = 0; ks < 2; ++ks) {
      const int aoff = (wv * 16 + c) * 128 + ks * 64 + g * 16;
      const short8 ah = *(const short8*)(AhB + swz128(aoff));
      const short8 al = *(const short8*)(AlB + swz128(aoff));
      #pragma unroll
      for (int cf = 0; cf < 8; ++cf) {
        const short8 wb =
            *(const short8*)(WtB + swz128((cf * 16 + c) * 128 + ks * 64 + g * 16));
        acc[cf] = mfma_bf16(ah, wb, acc[cf]);
        acc[cf] = mfma_bf16(al, wb, acc[cf]);
      }
    }
    __syncthreads();
  }

  if (which == 0) {
    // q scaled by log2(e) in f32 BEFORE the bf16 round (exp2-domain softmax)
    #pragma unroll
    for (int cf = 0; cf < 8; ++cf) {
      const float bb = bias[cf * 16 + c];
      #pragma unroll
      for (int r = 0; r < 4; ++r)
        qb[(size_t)(r0 + wv * 16 + g * 4 + r) * DOUT + cf * 16 + c] =
            bf16_rn((acc[cf][r] + bb) * LOG2E);
    }
  } else if (which == 1) {
    // K: bounce through swizzled LDS tile, then coalesced fragment-major stores
    char* const Ktile = lds;   // 16KB
    #pragma unroll
    for (int cf = 0; cf < 8; ++cf) {
      const float bb = bias[cf * 16 + c];
      #pragma unroll
      for (int r = 0; r < 4; ++r) {
        const int row = wv * 16 + g * 4 + r;
        *(unsigned short*)(Ktile + swzK(row * 256 + (cf * 16 + c) * 2)) =
            bf16_rn(acc[cf][r] + bb);
      }
    }
    __syncthreads();
    const int b2     = r0 >> 12;
    const int kblkG0 = (r0 & 4095) >> 5;
    #pragma unroll
    for (int j = 0; j < 4; ++j) {
      const int i    = tid + j * 256;
      const int kblk = i >> 9;
      const int rem  = i & 511;
      const int f    = rem >> 6;
      const int ln   = rem & 63;
      const int row  = kblk * 32 + (ln & 31);
      const int colb = f * 32 + (ln >> 5) * 16;
      const ushort8 v = *(const ushort8*)(Ktile + swzK(row * 256 + colb));
      *(ushort8*)((char*)kb +
          (((size_t)(b2 * 128 + kblkG0 + kblk) * 8 + f) * 64 + ln) * 16) = v;
    }
  } else {
    // fragment-major V (4 consecutive keys -> one us4 store)
    const int keybase = r0 + wv * 16 + g * 4;
    const int b2   = keybase >> 12;
    const int kblk = (keybase & 4095) >> 5;
    const int kk   = (keybase >> 4) & 1;
    const int h    = (keybase >> 3) & 1;
    const int e0   = keybase & 7;
    #pragma unroll
    for (int cf = 0; cf < 8; ++cf) {
      const float bb = bias[cf * 16 + c];
      const int col  = cf * 16 + c;
      const int dblk = col >> 5, l31 = col & 31;
      us4 pk;
      #pragma unroll
      for (int r = 0; r < 4; ++r) pk[r] = bf16_rn(acc[cf][r] + bb);
      *(us4*)(vt + (((((size_t)b2 * 128 + kblk) * 4 + dblk) * 2 + kk) * 64 +
                    h * 32 + l31) * 8 + e0) = pk;
    }
  }
}

// ---------------- flash attention: r10 loop, 8-way split ------------------
// Block: 512 thr = 8 waves = 8 kv-splits of one 32-query tile.
// Wave: 32 q x 512 keys, KVBLK=32/iter (16 iters), 32x32x16 MFMA.
// LDS 69.6KB -> 2 blocks/CU -> 16 waves/CU = 4/SIMD at the compiler's
// natural 128-VGPR choice. NO min-waves clause (r8/r18 spill lesson).
constexpr int NSPLIT = 8;
constexpr int QBLK   = 32;
constexpr int KVBLK  = 32;
constexpr int ITERS  = SEQLEN / NSPLIT / KVBLK;   // 16 (even)

__global__ __launch_bounds__(512) void attn_kernel(
    const unsigned short* __restrict__ qb,
    const unsigned short* __restrict__ kb,
    const unsigned short* __restrict__ vt,
    float* __restrict__ out)
{
  __shared__ __align__(16) float cmb[4][32][132];   // 67.6KB combine regions
  __shared__ float Ml[NSPLIT][32][2];               // 2KB

  // XCD swizzle (512 blocks = 8 XCD x 64): one batch per XCD-pair -> L2-fit
  const int bid = ((blockIdx.x & 7) << 6) | (blockIdx.x >> 3);
  const int qt  = bid & 127;
  const int b   = bid >> 7;
  const int tid = threadIdx.x;
  const int split = tid >> 6;   // 0..7
  const int lane  = tid & 63;
  const int ql = lane & 31;   // query column this lane owns
  const int h  = lane >> 5;   // half-wave

  const int q0 = qt * QBLK;

  // ---- Q B-fragments (once) ----
  short8 qf[8];
  {
    const char* qp = (const char*)(qb + (size_t)(b * SEQLEN + q0 + ql) * DOUT) + h * 16;
    #pragma unroll
    for (int f = 0; f < 8; ++f) qf[f] = *(const short8*)(qp + f * 32);
  }

  // ---- fragment-major streaming bases ----
  const int kblk0 = split * (SEQLEN / NSPLIT / 32);   // split*16
  const char* kfb = (const char*)kb + ((size_t)b * 128 + kblk0) * 8192 + lane * 16;
  const char* vfb = (const char*)vt + ((size_t)b * 128 + kblk0) * 8192 + lane * 16;

  f32x16 acc[4];
  #pragma unroll
  for (int d = 0; d < 4; ++d)
    #pragma unroll
    for (int r = 0; r < 16; ++r) acc[d][r] = 0.f;
  float mc = -1e30f, lc = 0.f;

  // preload: K tiles 0,1 (A,B); V tile 0
  short8 kfA[8], kfB[8], vf[4][2];
  #pragma unroll
  for (int f = 0; f < 8; ++f) kfA[f] = *(const short8*)(kfb + f * 1024);
  #pragma unroll
  for (int f = 0; f < 8; ++f) kfB[f] = *(const short8*)(kfb + 8192 + f * 1024);
  kfb += 16384;                                   // -> tile 2
  #pragma unroll
  for (int d = 0; d < 4; ++d)
    #pragma unroll
    for (int kk = 0; kk < 2; ++kk)
      vf[d][kk] = *(const short8*)(vfb + (d * 2 + kk) * 1024);

  auto body = [&](short8 (&kf)[8], int t) {
    // ---- S^T = K Q^T, two independent chains (4-deep each) ----
    f32x16 s0, s1;
    #pragma unroll
    for (int r = 0; r < 16; ++r) { s0[r] = 0.f; s1[r] = 0.f; }
    __builtin_amdgcn_s_setprio(1);
    #pragma unroll
    for (int f = 0; f < 4; ++f) s0 = mfma32(kf[f], qf[f], s0);
    #pragma unroll
    for (int f = 0; f < 4; ++f) s1 = mfma32(kf[f + 4], qf[f + 4], s1);
    __builtin_amdgcn_s_setprio(0);

    // prefetch K(t+2) into the buffer just consumed (depth-2)
    if (t + 2 < ITERS) {
      #pragma unroll
      for (int f = 0; f < 8; ++f) kf[f] = *(const short8*)(kfb + f * 1024);
      kfb += 8192;
    }

    float s[16];
    #pragma unroll
    for (int r = 0; r < 16; ++r) s[r] = s0[r] + s1[r];

    // ---- softmax, defer-max (THR=11 log2 units: P <= 2048) ----
    float m01 = fmaxf(fmaxf(s[0],  s[1]),  s[2]);
    float m02 = fmaxf(fmaxf(s[3],  s[4]),  s[5]);
    float m03 = fmaxf(fmaxf(s[6],  s[7]),  s[8]);
    float m04 = fmaxf(fmaxf(s[9],  s[10]), s[11]);
    float m05 = fmaxf(fmaxf(s[12], s[13]), s[14]);
    float m11 = fmaxf(fmaxf(m01, m02), m03);
    float m12 = fmaxf(fmaxf(m04, m05), s[15]);
    float tm  = fmaxf(m11, m12);
    if (!__all(tm <= mc + 11.f)) {
      float tr = fmaxf(tm, __shfl_xor(tm, 32));
      const float mnew  = fmaxf(mc, tr);
      const float sc    = exp2n(mc - mnew);
      mc = mnew;
      lc *= sc;
      #pragma unroll
      for (int d = 0; d < 4; ++d)
        #pragma unroll
        for (int r = 0; r < 16; ++r) acc[d][r] *= sc;
    }
    float p[16];
    #pragma unroll
    for (int r = 0; r < 16; ++r) p[r] = exp2n(s[r] - mc);   // native v_exp_f32
    float a0 = (p[0]+p[1]) + (p[2]+p[3]);
    float a1 = (p[4]+p[5]) + (p[6]+p[7]);
    float a2 = (p[8]+p[9]) + (p[10]+p[11]);
    float a3 = (p[12]+p[13]) + (p[14]+p[15]);
    lc += (a0 + a1) + (a2 + a3);

    // ---- P -> B-fragments in-register (T12) ----
    short8 pfrag[2];
    #pragma unroll
    for (int kk = 0; kk < 2; ++kk) {
      unsigned int A  = cvt_pk(p[kk * 8 + 0], p[kk * 8 + 1]);
      unsigned int Bv = cvt_pk(p[kk * 8 + 2], p[kk * 8 + 3]);
      unsigned int C  = cvt_pk(p[kk * 8 + 4], p[kk * 8 + 5]);
      unsigned int Dv = cvt_pk(p[kk * 8 + 6], p[kk * 8 + 7]);
      permswap(A, C);
      permswap(Bv, Dv);
      const u32x4 w = {A, Bv, C, Dv};
      pfrag[kk] = __builtin_bit_cast(short8, w);
    }

    // ---- O^T += V^T P^T (4 independent 2-deep chains) ----
    __builtin_amdgcn_s_setprio(1);
    #pragma unroll
    for (int d = 0; d < 4; ++d)
      #pragma unroll
      for (int kk = 0; kk < 2; ++kk)
        acc[d] = mfma32(vf[d][kk], pfrag[kk], acc[d]);
    __builtin_amdgcn_s_setprio(0);

    // prefetch V(t+1)
    if (t + 1 < ITERS) {
      vfb += 8192;
      #pragma unroll
      for (int d = 0; d < 4; ++d)
        #pragma unroll
        for (int kk = 0; kk < 2; ++kk)
          vf[d][kk] = *(const short8*)(vfb + (d * 2 + kk) * 1024);
    }
  };

  for (int t = 0; t < ITERS; t += 2) {
    body(kfA, t);
    body(kfB, t + 1);
  }

  // ---- cross-split combine (exp2 domain), 8 partials ----
  lc += __shfl_xor(lc, 32);
  if (lane < 32) { Ml[split][ql][0] = mc; Ml[split][ql][1] = lc; }
  __syncthreads();

  float mg = -1e30f, lsum = 0.f;
  #pragma unroll
  for (int s2 = 0; s2 < NSPLIT; ++s2) mg = fmaxf(mg, Ml[s2][ql][0]);
  #pragma unroll
  for (int s2 = 0; s2 < NSPLIT; ++s2)
    lsum += Ml[s2][ql][1] * exp2n(Ml[s2][ql][0] - mg);
  const float fac = exp2n(mc - mg);
  #pragma unroll
  for (int d = 0; d < 4; ++d)
    #pragma unroll
    for (int r = 0; r < 16; ++r) acc[d][r] *= fac;

  auto writeReg = [&](float* reg) {
    #pragma unroll
    for (int d = 0; d < 4; ++d)
      #pragma unroll
      for (int rr = 0; rr < 4; ++rr) {
        const f32x4 v = {acc[d][rr*4+0], acc[d][rr*4+1], acc[d][rr*4+2], acc[d][rr*4+3]};
        *(f32x4*)(reg + ql * 132 + d * 32 + rr * 8 + h * 4) = v;
      }
  };
  auto addReg = [&](const float* reg) {
    #pragma unroll
    for (int d = 0; d < 4; ++d)
      #pragma unroll
      for (int rr = 0; rr < 4; ++rr) {
        const f32x4 v = *(const f32x4*)(reg + ql * 132 + d * 32 + rr * 8 + h * 4);
        acc[d][rr*4+0] += v.x; acc[d][rr*4+1] += v.y;
        acc[d][rr*4+2] += v.z; acc[d][rr*4+3] += v.w;
      }
  };

  // tree: {4-7} write -> {0-3} add -> {2,3} write -> {0,1} add
  //       -> {1} writes -> {0} adds -> out
  if (split >= 4) writeReg(&cmb[split - 4][0][0]);
  __syncthreads();
  if (split < 4) addReg(&cmb[split][0][0]);
  __syncthreads();
  if (split == 2 || split == 3) writeReg(&cmb[split - 2][0][0]);
  __syncthreads();
  if (split == 0 || split == 1) addReg(&cmb[split][0][0]);
  __syncthreads();
  if (split == 1) writeReg(&cmb[0][0][0]);
  __syncthreads();
  if (split == 0) {
    addReg(&cmb[0][0][0]);
    const float inv = 1.f / lsum;
    float* const op = out + (size_t)(b * SEQLEN + q0 + ql) * DOUT;
    #pragma unroll
    for (int d = 0; d < 4; ++d)
      #pragma unroll
      for (int rr = 0; rr < 4; ++rr) {
        f32x4 o;
        o.x = acc[d][rr*4+0] * inv;
        o.y = acc[d][rr*4+1] * inv;
        o.z = acc[d][rr*4+2] * inv;
        o.w = acc[d][rr*4+3] * inv;
        *(f32x4*)(op + d * 32 + rr * 8 + h * 4) = o;
      }
  }
}

extern "C" void kernel_launch(void* const* d_in, const int* in_sizes, int n_in,
                              void* d_out, int out_size, void* d_ws, size_t ws_size,
                              hipStream_t stream) {
  const float* x    = (const float*)d_in[0];
  const float* cond = (const float*)d_in[1];
  const float* Wq   = (const float*)d_in[2];
  const float* bq   = (const float*)d_in[3];
  const float* Wk   = (const float*)d_in[4];
  const float* bk   = (const float*)d_in[5];
  const float* Wv   = (const float*)d_in[6];
  const float* bv   = (const float*)d_in[7];
  float* out = (float*)d_out;

  unsigned short* qb = (unsigned short*)d_ws;                 // 4MB (log2e-scaled)
  unsigned short* kb = qb + (size_t)ROWS * DOUT;              // 4MB fragment-major
  unsigned short* vt = kb + (size_t)ROWS * DOUT;              // 4MB fragment-major

  proj_kernel<<<dim3(ROWS / 64, 3), 256, 0, stream>>>(
      x, cond, Wq, bq, Wk, bk, Wv, bv, qb, kb, vt);

  attn_kernel<<<dim3(BATCH * (SEQLEN / QBLK)), 512, 0, stream>>>(
      qb, kb, vt, out);
}

// Round 20
// 71.378 us; speedup vs baseline: 5.9535x; 1.0436x over previous
//
#include <hip/hip_runtime.h>
#include <hip/hip_bf16.h>

// CrossAttention: q = x@Wq+bq; k = cond@Wk+bk; v = cond@Wv+bv
// scores = q@k^T (UNSCALED); attn = softmax(scores); out = attn@v
// B=4, Lq=Lk=4096, IN=COND=256, OUT_DIM=128. Output fp32.
//
// FINAL = r10/r17 configuration (measured best: 71.42us total; attn ~53.8us).
// Ledger of falsified alternatives: T15 pipeline (r11), waves_per_eu (r12),
// sched_barrier pinning (r13), async-LDS + q-sharing (r14), 16x16 4-wave
// (r15), k/v-fused proj (r16), NSPLIT=8 pinned -> spill (r18), NSPLIT=8
// unpinned -> 58us (r19). Binding constraint: per-wave serial L2 chain at
// the 2-waves/SIMD occupancy the ~190-reg live set permits.

typedef __attribute__((ext_vector_type(8))) short short8;
typedef __attribute__((ext_vector_type(8))) unsigned short ushort8;
typedef __attribute__((ext_vector_type(4))) unsigned short us4;
typedef __attribute__((ext_vector_type(4))) float f32x4;
typedef __attribute__((ext_vector_type(16))) float f32x16;
typedef __attribute__((ext_vector_type(4))) unsigned int u32x4;
typedef __bf16 bf16x8 __attribute__((ext_vector_type(8)));

constexpr int BATCH  = 4;
constexpr int SEQLEN = 4096;   // Lq == Lk
constexpr int DIN    = 256;
constexpr int DOUT   = 128;
constexpr int ROWS   = BATCH * SEQLEN;  // 16384
constexpr float LOG2E = 1.4426950408889634f;

static __device__ __forceinline__ unsigned short bf16_rn(float f) {
  unsigned int u = __builtin_bit_cast(unsigned int, f);
  unsigned int r = u + 0x7FFFu + ((u >> 16) & 1u);
  return (unsigned short)(r >> 16);
}
static __device__ __forceinline__ float bf16_f32(unsigned short h) {
  return __builtin_bit_cast(float, (unsigned int)h << 16);
}
static __device__ __forceinline__ float exp2n(float x) {
  return __builtin_amdgcn_exp2f(x);    // native v_exp_f32
}

static __device__ __forceinline__ f32x4 mfma_bf16(short8 a, short8 b, f32x4 c) {
  return __builtin_amdgcn_mfma_f32_16x16x32_bf16(
      __builtin_bit_cast(bf16x8, a), __builtin_bit_cast(bf16x8, b), c, 0, 0, 0);
}
static __device__ __forceinline__ f32x16 mfma32(short8 a, short8 b, f32x16 c) {
  return __builtin_amdgcn_mfma_f32_32x32x16_bf16(
      __builtin_bit_cast(bf16x8, a), __builtin_bit_cast(bf16x8, b), c, 0, 0, 0);
}

// D = [bf16(S0) | bf16(S1)<<16]
static __device__ __forceinline__ unsigned int cvt_pk(float lo, float hi) {
  unsigned int r;
  asm("v_cvt_pk_bf16_f32 %0, %1, %2" : "=v"(r) : "v"(lo), "v"(hi));
  return r;
}
// v_permlane32_swap_b32 vdst, vsrc: a.hi32lanes <-> b.lo32lanes
static __device__ __forceinline__ void permswap(unsigned int& a, unsigned int& b) {
  asm("v_permlane32_swap_b32 %0, %1" : "+v"(a), "+v"(b));
}

static __device__ __forceinline__ int swz128(int a) {
  return a ^ (((a >> 7) & 7) << 4);
}
// K-bounce tile (row stride 256B): fold row bits 0-3 into byte bits 4-7
static __device__ __forceinline__ int swzK(int a) {
  return a ^ (((a >> 8) & 15) << 4);
}

// Fragment-major global layouts (written by proj, read coalesced by attn):
//  K: kfb[b][kblk(128)][f(8)][lane(64)] x 16B
//  V: vfb[b][kblk(128)][dblk(4)][kk(2)][lane(64)] x 16B

// ---------------- projection via MFMA, split-precision --------------------
__global__ __launch_bounds__(256) void proj_kernel(
    const float* __restrict__ x, const float* __restrict__ cond,
    const float* __restrict__ Wq, const float* __restrict__ bq,
    const float* __restrict__ Wk, const float* __restrict__ bk,
    const float* __restrict__ Wv, const float* __restrict__ bv,
    unsigned short* __restrict__ qb, unsigned short* __restrict__ kb,
    unsigned short* __restrict__ vt)
{
  const int which = blockIdx.y;
  const float* __restrict__ src  = (which == 0) ? x  : cond;
  const float* __restrict__ W    = (which == 0) ? Wq : (which == 1 ? Wk : Wv);
  const float* __restrict__ bias = (which == 0) ? bq : (which == 1 ? bk : bv);
  const int r0 = blockIdx.x * 64;

  __shared__ __align__(16) char lds[32768];
  char* const AhB = lds;
  char* const AlB = lds + 8192;
  char* const WtB = lds + 16384;

  const int tid  = threadIdx.x;
  const int wv   = tid >> 6;
  const int lane = tid & 63;
  const int g    = lane >> 4;
  const int c    = lane & 15;

  f32x4 acc[8];
  #pragma unroll
  for (int cf = 0; cf < 8; ++cf) acc[cf] = (f32x4){0.f, 0.f, 0.f, 0.f};

  for (int kt = 0; kt < 4; ++kt) {
    #pragma unroll
    for (int i = 0; i < 4; ++i) {
      const int idx = tid + i * 256;
      const int row = idx >> 4, f4 = idx & 15;
      const float4 a4 =
          *(const float4*)(src + (size_t)(r0 + row) * DIN + kt * 64 + f4 * 4);
      us4 hi, lo;
      const float av[4] = {a4.x, a4.y, a4.z, a4.w};
      #pragma unroll
      for (int e = 0; e < 4; ++e) {
        hi[e] = bf16_rn(av[e]);
        lo[e] = bf16_rn(av[e] - bf16_f32(hi[e]));
      }
      const int off = swz128(row * 128 + f4 * 8);
      *(us4*)(AhB + off) = hi;
      *(us4*)(AlB + off) = lo;
    }
    {
      const int col = tid & 127, half = tid >> 7;
      #pragma unroll
      for (int j = 0; j < 4; ++j) {
        const int k0 = half * 32 + j * 8;
        ushort8 wb;
        #pragma unroll
        for (int e = 0; e < 8; ++e)
          wb[e] = bf16_rn(W[(size_t)(kt * 64 + k0 + e) * DOUT + col]);
        *(ushort8*)(WtB + swz128(col * 128 + k0 * 2)) = wb;
      }
    }
    __syncthreads();

    #pragma unroll
    for (int ks = 0; ks < 2; ++ks) {
      const int aoff = (wv * 16 + c) * 128 + ks * 64 + g * 16;
      const short8 ah = *(const short8*)(AhB + swz128(aoff));
      const short8 al = *(const short8*)(AlB + swz128(aoff));
      #pragma unroll
      for (int cf = 0; cf < 8; ++cf) {
        const short8 wb =
            *(const short8*)(WtB + swz128((cf * 16 + c) * 128 + ks * 64 + g * 16));
        acc[cf] = mfma_bf16(ah, wb, acc[cf]);
        acc[cf] = mfma_bf16(al, wb, acc[cf]);
      }
    }
    __syncthreads();
  }

  if (which == 0) {
    // q scaled by log2(e) in f32 BEFORE the bf16 round (exp2-domain softmax)
    #pragma unroll
    for (int cf = 0; cf < 8; ++cf) {
      const float bb = bias[cf * 16 + c];
      #pragma unroll
      for (int r = 0; r < 4; ++r)
        qb[(size_t)(r0 + wv * 16 + g * 4 + r) * DOUT + cf * 16 + c] =
            bf16_rn((acc[cf][r] + bb) * LOG2E);
    }
  } else if (which == 1) {
    // K: bounce through swizzled LDS tile, then coalesced fragment-major stores
    char* const Ktile = lds;   // 16KB
    #pragma unroll
    for (int cf = 0; cf < 8; ++cf) {
      const float bb = bias[cf * 16 + c];
      #pragma unroll
      for (int r = 0; r < 4; ++r) {
        const int row = wv * 16 + g * 4 + r;
        *(unsigned short*)(Ktile + swzK(row * 256 + (cf * 16 + c) * 2)) =
            bf16_rn(acc[cf][r] + bb);
      }
    }
    __syncthreads();
    const int b2     = r0 >> 12;
    const int kblkG0 = (r0 & 4095) >> 5;
    #pragma unroll
    for (int j = 0; j < 4; ++j) {
      const int i    = tid + j * 256;
      const int kblk = i >> 9;
      const int rem  = i & 511;
      const int f    = rem >> 6;
      const int ln   = rem & 63;
      const int row  = kblk * 32 + (ln & 31);
      const int colb = f * 32 + (ln >> 5) * 16;
      const ushort8 v = *(const ushort8*)(Ktile + swzK(row * 256 + colb));
      *(ushort8*)((char*)kb +
          (((size_t)(b2 * 128 + kblkG0 + kblk) * 8 + f) * 64 + ln) * 16) = v;
    }
  } else {
    // fragment-major V (4 consecutive keys -> one us4 store)
    const int keybase = r0 + wv * 16 + g * 4;
    const int b2   = keybase >> 12;
    const int kblk = (keybase & 4095) >> 5;
    const int kk   = (keybase >> 4) & 1;
    const int h    = (keybase >> 3) & 1;
    const int e0   = keybase & 7;
    #pragma unroll
    for (int cf = 0; cf < 8; ++cf) {
      const float bb = bias[cf * 16 + c];
      const int col  = cf * 16 + c;
      const int dblk = col >> 5, l31 = col & 31;
      us4 pk;
      #pragma unroll
      for (int r = 0; r < 4; ++r) pk[r] = bf16_rn(acc[cf][r] + bb);
      *(us4*)(vt + (((((size_t)b2 * 128 + kblk) * 4 + dblk) * 2 + kk) * 64 +
                    h * 32 + l31) * 8 + e0) = pk;
    }
  }
}

// ---------------- flash attention: register-resident, no LDS in loop ------
// Block: 256 thr = 4 waves = 4 kv-splits of one 32-query tile.
// Wave: 32 q x 1024 keys, KVBLK=32/iter (32 iters), 32x32x16 MFMA.
// Depth-2 K prefetch (static A/B buffers); depth-1 V; native-exp2 softmax.
constexpr int NSPLIT = 4;
constexpr int QBLK   = 32;
constexpr int KVBLK  = 32;
constexpr int ITERS  = SEQLEN / NSPLIT / KVBLK;   // 32 (even)

__global__ __launch_bounds__(256, 2) void attn_kernel(
    const unsigned short* __restrict__ qb,
    const unsigned short* __restrict__ kb,
    const unsigned short* __restrict__ vt,
    float* __restrict__ out)
{
  __shared__ __align__(16) float cmb[2][32][132];   // 33.8KB combine buffer
  __shared__ float Ml[NSPLIT][32][2];               // 1KB

  // XCD swizzle (512 blocks = 8 XCD x 64): one batch per XCD-pair -> L2-fit
  const int bid = ((blockIdx.x & 7) << 6) | (blockIdx.x >> 3);
  const int qt  = bid & 127;
  const int b   = bid >> 7;
  const int tid = threadIdx.x;
  const int split = tid >> 6;
  const int lane  = tid & 63;
  const int ql = lane & 31;   // query column this lane owns
  const int h  = lane >> 5;   // half-wave

  const int q0 = qt * QBLK;

  // ---- Q B-fragments (once) ----
  short8 qf[8];
  {
    const char* qp = (const char*)(qb + (size_t)(b * SEQLEN + q0 + ql) * DOUT) + h * 16;
    #pragma unroll
    for (int f = 0; f < 8; ++f) qf[f] = *(const short8*)(qp + f * 32);
  }

  // ---- fragment-major streaming bases ----
  const int kblk0 = split * (SEQLEN / NSPLIT / 32);   // split*32
  const char* kfb = (const char*)kb + ((size_t)b * 128 + kblk0) * 8192 + lane * 16;
  const char* vfb = (const char*)vt + ((size_t)b * 128 + kblk0) * 8192 + lane * 16;

  f32x16 acc[4];
  #pragma unroll
  for (int d = 0; d < 4; ++d)
    #pragma unroll
    for (int r = 0; r < 16; ++r) acc[d][r] = 0.f;
  float mc = -1e30f, lc = 0.f;

  // preload: K tiles 0,1 (A,B); V tile 0
  short8 kfA[8], kfB[8], vf[4][2];
  #pragma unroll
  for (int f = 0; f < 8; ++f) kfA[f] = *(const short8*)(kfb + f * 1024);
  #pragma unroll
  for (int f = 0; f < 8; ++f) kfB[f] = *(const short8*)(kfb + 8192 + f * 1024);
  kfb += 16384;                                   // -> tile 2
  #pragma unroll
  for (int d = 0; d < 4; ++d)
    #pragma unroll
    for (int kk = 0; kk < 2; ++kk)
      vf[d][kk] = *(const short8*)(vfb + (d * 2 + kk) * 1024);

  auto body = [&](short8 (&kf)[8], int t) {
    // ---- S^T = K Q^T, two independent chains (4-deep each) ----
    f32x16 s0, s1;
    #pragma unroll
    for (int r = 0; r < 16; ++r) { s0[r] = 0.f; s1[r] = 0.f; }
    __builtin_amdgcn_s_setprio(1);
    #pragma unroll
    for (int f = 0; f < 4; ++f) s0 = mfma32(kf[f], qf[f], s0);
    #pragma unroll
    for (int f = 0; f < 4; ++f) s1 = mfma32(kf[f + 4], qf[f + 4], s1);
    __builtin_amdgcn_s_setprio(0);

    // prefetch K(t+2) into the buffer just consumed (depth-2)
    if (t + 2 < ITERS) {
      #pragma unroll
      for (int f = 0; f < 8; ++f) kf[f] = *(const short8*)(kfb + f * 1024);
      kfb += 8192;
    }

    float s[16];
    #pragma unroll
    for (int r = 0; r < 16; ++r) s[r] = s0[r] + s1[r];

    // ---- softmax, defer-max (THR=11 log2 units: P <= 2048) ----
    float m01 = fmaxf(fmaxf(s[0],  s[1]),  s[2]);
    float m02 = fmaxf(fmaxf(s[3],  s[4]),  s[5]);
    float m03 = fmaxf(fmaxf(s[6],  s[7]),  s[8]);
    float m04 = fmaxf(fmaxf(s[9],  s[10]), s[11]);
    float m05 = fmaxf(fmaxf(s[12], s[13]), s[14]);
    float m11 = fmaxf(fmaxf(m01, m02), m03);
    float m12 = fmaxf(fmaxf(m04, m05), s[15]);
    float tm  = fmaxf(m11, m12);
    if (!__all(tm <= mc + 11.f)) {
      float tr = fmaxf(tm, __shfl_xor(tm, 32));
      const float mnew  = fmaxf(mc, tr);
      const float sc    = exp2n(mc - mnew);
      mc = mnew;
      lc *= sc;
      #pragma unroll
      for (int d = 0; d < 4; ++d)
        #pragma unroll
        for (int r = 0; r < 16; ++r) acc[d][r] *= sc;
    }
    float p[16];
    #pragma unroll
    for (int r = 0; r < 16; ++r) p[r] = exp2n(s[r] - mc);   // native v_exp_f32
    float a0 = (p[0]+p[1]) + (p[2]+p[3]);
    float a1 = (p[4]+p[5]) + (p[6]+p[7]);
    float a2 = (p[8]+p[9]) + (p[10]+p[11]);
    float a3 = (p[12]+p[13]) + (p[14]+p[15]);
    lc += (a0 + a1) + (a2 + a3);

    // ---- P -> B-fragments in-register (T12) ----
    short8 pfrag[2];
    #pragma unroll
    for (int kk = 0; kk < 2; ++kk) {
      unsigned int A  = cvt_pk(p[kk * 8 + 0], p[kk * 8 + 1]);
      unsigned int Bv = cvt_pk(p[kk * 8 + 2], p[kk * 8 + 3]);
      unsigned int C  = cvt_pk(p[kk * 8 + 4], p[kk * 8 + 5]);
      unsigned int Dv = cvt_pk(p[kk * 8 + 6], p[kk * 8 + 7]);
      permswap(A, C);
      permswap(Bv, Dv);
      const u32x4 w = {A, Bv, C, Dv};
      pfrag[kk] = __builtin_bit_cast(short8, w);
    }

    // ---- O^T += V^T P^T (4 independent 2-deep chains) ----
    __builtin_amdgcn_s_setprio(1);
    #pragma unroll
    for (int d = 0; d < 4; ++d)
      #pragma unroll
      for (int kk = 0; kk < 2; ++kk)
        acc[d] = mfma32(vf[d][kk], pfrag[kk], acc[d]);
    __builtin_amdgcn_s_setprio(0);

    // prefetch V(t+1)
    if (t + 1 < ITERS) {
      vfb += 8192;
      #pragma unroll
      for (int d = 0; d < 4; ++d)
        #pragma unroll
        for (int kk = 0; kk < 2; ++kk)
          vf[d][kk] = *(const short8*)(vfb + (d * 2 + kk) * 1024);
    }
  };

  for (int t = 0; t < ITERS; t += 2) {
    body(kfA, t);
    body(kfB, t + 1);
  }

  // ---- cross-split combine (exp2 domain) ----
  lc += __shfl_xor(lc, 32);
  if (lane < 32) { Ml[split][ql][0] = mc; Ml[split][ql][1] = lc; }
  __syncthreads();

  float mg = -1e30f, lsum = 0.f;
  #pragma unroll
  for (int s2 = 0; s2 < NSPLIT; ++s2) mg = fmaxf(mg, Ml[s2][ql][0]);
  #pragma unroll
  for (int s2 = 0; s2 < NSPLIT; ++s2)
    lsum += Ml[s2][ql][1] * exp2n(Ml[s2][ql][0] - mg);
  const float fac = exp2n(mc - mg);
  #pragma unroll
  for (int d = 0; d < 4; ++d)
    #pragma unroll
    for (int r = 0; r < 16; ++r) acc[d][r] *= fac;

  // tree: {1,3} write -> {0,2} add -> {2} writes -> {0} adds -> out
  if (split & 1) {
    float* reg = &cmb[split >> 1][0][0];
    #pragma unroll
    for (int d = 0; d < 4; ++d)
      #pragma unroll
      for (int rr = 0; rr < 4; ++rr) {
        const f32x4 v = {acc[d][rr*4+0], acc[d][rr*4+1], acc[d][rr*4+2], acc[d][rr*4+3]};
        *(f32x4*)(reg + ql * 132 + d * 32 + rr * 8 + h * 4) = v;
      }
  }
  __syncthreads();
  if (!(split & 1)) {
    const float* reg = &cmb[split >> 1][0][0];
    #pragma unroll
    for (int d = 0; d < 4; ++d)
      #pragma unroll
      for (int rr = 0; rr < 4; ++rr) {
        const f32x4 v = *(const f32x4*)(reg + ql * 132 + d * 32 + rr * 8 + h * 4);
        acc[d][rr*4+0] += v.x; acc[d][rr*4+1] += v.y;
        acc[d][rr*4+2] += v.z; acc[d][rr*4+3] += v.w;
      }
  }
  __syncthreads();
  if (split == 2) {
    float* reg = &cmb[0][0][0];
    #pragma unroll
    for (int d = 0; d < 4; ++d)
      #pragma unroll
      for (int rr = 0; rr < 4; ++rr) {
        const f32x4 v = {acc[d][rr*4+0], acc[d][rr*4+1], acc[d][rr*4+2], acc[d][rr*4+3]};
        *(f32x4*)(reg + ql * 132 + d * 32 + rr * 8 + h * 4) = v;
      }
  }
  __syncthreads();
  if (split == 0) {
    const float* reg = &cmb[0][0][0];
    const float inv = 1.f / lsum;
    float* const op = out + (size_t)(b * SEQLEN + q0 + ql) * DOUT;
    #pragma unroll
    for (int d = 0; d < 4; ++d)
      #pragma unroll
      for (int rr = 0; rr < 4; ++rr) {
        const f32x4 v = *(const f32x4*)(reg + ql * 132 + d * 32 + rr * 8 + h * 4);
        f32x4 o;
        o.x = (acc[d][rr*4+0] + v.x) * inv;
        o.y = (acc[d][rr*4+1] + v.y) * inv;
        o.z = (acc[d][rr*4+2] + v.z) * inv;
        o.w = (acc[d][rr*4+3] + v.w) * inv;
        *(f32x4*)(op + d * 32 + rr * 8 + h * 4) = o;
      }
  }
}

extern "C" void kernel_launch(void* const* d_in, const int* in_sizes, int n_in,
                              void* d_out, int out_size, void* d_ws, size_t ws_size,
                              hipStream_t stream) {
  const float* x    = (const float*)d_in[0];
  const float* cond = (const float*)d_in[1];
  const float* Wq   = (const float*)d_in[2];
  const float* bq   = (const float*)d_in[3];
  const float* Wk   = (const float*)d_in[4];
  const float* bk   = (const float*)d_in[5];
  const float* Wv   = (const float*)d_in[6];
  const float* bv   = (const float*)d_in[7];
  float* out = (float*)d_out;

  unsigned short* qb = (unsigned short*)d_ws;                 // 4MB (log2e-scaled)
  unsigned short* kb = qb + (size_t)ROWS * DOUT;              // 4MB fragment-major
  unsigned short* vt = kb + (size_t)ROWS * DOUT;              // 4MB fragment-major

  proj_kernel<<<dim3(ROWS / 64, 3), 256, 0, stream>>>(
      x, cond, Wq, bq, Wk, bk, Wv, bv, qb, kb, vt);

  attn_kernel<<<dim3(BATCH * (SEQLEN / QBLK)), 256, 0, stream>>>(
      qb, kb, vt, out);
}